// Round 5
// baseline (282.569 us; speedup 1.0000x reference)
//
#include <hip/hip_runtime.h>
#include <stdint.h>
#include <stddef.h>

typedef unsigned short u16;
typedef unsigned int   u32;

typedef __attribute__((ext_vector_type(8))) short bf16x8;
typedef __attribute__((ext_vector_type(4))) float f32x4;

__device__ __forceinline__ float b2f(u16 u)    { return __uint_as_float(((u32)u) << 16); }
__device__ __forceinline__ u16 f2b(float f){
  u32 x = __float_as_uint(f);
  return (u16)((x + 0x7FFFu + ((x >> 16) & 1u)) >> 16);
}

// ---------------------------------------------------------------------------
// K0a: x[b][c][w] FLOAT32 -> xt[b][w][c] bf16 (fused transpose+downconvert).
// B=4, C=256, W=8192.  grid (128 w-tiles, 4 c-tiles, 4 b) x 256 thr; 64x64 tile.
// ---------------------------------------------------------------------------
__global__ __launch_bounds__(256) void k_transpose(const float* __restrict__ x, u16* __restrict__ xt){
  __shared__ u16 tile[64 * 65];
  const int wt = blockIdx.x, ct = blockIdx.y, b = blockIdx.z;
  const int W0 = wt << 6, C0 = ct << 6;
  const int t = threadIdx.x;
#pragma unroll
  for (int it = 0; it < 4; ++it){
    const int task = t + (it << 8);          // 0..1023
    const int c = task >> 4, u = task & 15;  // c<64, u<16 (float4 chunks of 64-wide row)
    const float4 d = *(const float4*)(x + ((size_t)((b << 8) + C0 + c) << 13) + W0 + (u << 2));
    const int base = c * 65 + (u << 2);
    tile[base + 0] = f2b(d.x); tile[base + 1] = f2b(d.y);
    tile[base + 2] = f2b(d.z); tile[base + 3] = f2b(d.w);
  }
  __syncthreads();
#pragma unroll
  for (int it = 0; it < 2; ++it){
    const int task = t + (it << 8);          // 0..511
    const int wr = task >> 3, cu = task & 7; // wr<64, cu<8 (8 bf16 per chunk)
    const int cb = cu << 3;
    u32 a0 = (u32)tile[(cb + 0) * 65 + wr] | ((u32)tile[(cb + 1) * 65 + wr] << 16);
    u32 a1 = (u32)tile[(cb + 2) * 65 + wr] | ((u32)tile[(cb + 3) * 65 + wr] << 16);
    u32 a2 = (u32)tile[(cb + 4) * 65 + wr] | ((u32)tile[(cb + 5) * 65 + wr] << 16);
    u32 a3 = (u32)tile[(cb + 6) * 65 + wr] | ((u32)tile[(cb + 7) * 65 + wr] << 16);
    uint4 val = make_uint4(a0, a1, a2, a3);
    *(uint4*)(xt + ((size_t)((b << 13) + W0 + wr) << 8) + C0 + cb) = val;
  }
}

// ---------------------------------------------------------------------------
// K0b: build combined weight matrix Wall[896][256] (bf16) + fp32 bias ball[896]
// from FLOAT32 inputs.  rows 0-255: w1/b1, 256-511: w2/b2, 512-767: w3/b3,
// rows 768-831: Wf/bf (fc folded conv branch), 832-895: zero pad.
// grid 896 x 256 threads.
// ---------------------------------------------------------------------------
__global__ __launch_bounds__(256) void k_build(const float* __restrict__ w1, const float* __restrict__ b1,
                                               const float* __restrict__ w2, const float* __restrict__ b2,
                                               const float* __restrict__ w3, const float* __restrict__ b3,
                                               const float* __restrict__ fcw,
                                               u16* __restrict__ Wall, float* __restrict__ ball){
  const int r = blockIdx.x, c = threadIdx.x;
  float v = 0.f, bv = 0.f;
  if (r < 256){      v = w1[(r << 8) + c];          bv = b1[r]; }
  else if (r < 512){ v = w2[((r - 256) << 8) + c];  bv = b2[r - 256]; }
  else if (r < 768){ v = w3[((r - 512) << 8) + c];  bv = b3[r - 512]; }
  else if (r < 832){
    const int d = r - 768;
    float s = 0.f, sbias = 0.f;
#pragma unroll
    for (int h = 0; h < 4; ++h){
      const int ch = (h << 6) + d;
      const float f1 = fcw[h], f2 = fcw[4 + h], f3 = fcw[8 + h];
      s     += f1 * w1[(ch << 8) + c] + f2 * w2[(ch << 8) + c] + f3 * w3[(ch << 8) + c];
      sbias += f1 * b1[ch] + f2 * b2[ch] + f3 * b3[ch];
    }
    v = s; bv = sbias;
  }
  Wall[(r << 8) + c] = f2b(v);
  if (c == 0) ball[r] = bv;
}

// ---------------------------------------------------------------------------
// K1: GEMM  qkvt[b][m][w] = Wall[m][:] . xt[b][w][:] + ball[m]  (CHANNEL-MAJOR
// output this round).  M=896 (7 tiles of 128), N=32768 (b,w), K=256 (BK=64).
// 256 threads = 4 waves in 2x2; each wave 64x64 via 4x4 grid of 16x16x32 MFMA.
// Epilogue: per-reg 2B stores -> each instr writes 4 m-rows x 32B aligned
// full sectors (no partial-sector RMW; was 257 MB WRITE_SIZE, ideal 54.5).
// grid (7, 256).
// ---------------------------------------------------------------------------
__global__ __launch_bounds__(256) void gemm_qkv(const u16* __restrict__ Wall, const float* __restrict__ ball,
                                                const u16* __restrict__ xt, u16* __restrict__ qkvt){
  __shared__ __align__(16) u16 As[128 * 64];
  __shared__ __align__(16) u16 Bs[128 * 64];
  const int mt = blockIdx.x, nt = blockIdx.y;
  const int b = nt >> 6;
  const int w0 = (nt & 63) << 7;
  const int tid = threadIdx.x;
  const int wave = tid >> 6, lane = tid & 63;
  const int wy = wave >> 1, wx = wave & 1;
  const int m0 = mt << 7;
  const int quad = lane >> 4, l15 = lane & 15;
  f32x4 acc[4][4] = {};

  for (int kc = 0; kc < 256; kc += 64){
    // stage 128x64 A-tile and B-tile: 1024 16B-chunks each, 4 per thread
    uint4 ra[4], rb[4];
#pragma unroll
    for (int k = 0; k < 4; ++k){
      const int cid = tid + (k << 8);          // 0..1023
      const int row = cid >> 3, u = cid & 7;   // row<128, unit<8 (8 bf16 each)
      ra[k] = *(const uint4*)(Wall + ((m0 + row) << 8) + kc + (u << 3));
      rb[k] = *(const uint4*)(xt + (((size_t)((b << 13) + w0 + row)) << 8) + kc + (u << 3));
    }
    __syncthreads();   // previous iteration's LDS reads complete before overwrite
#pragma unroll
    for (int k = 0; k < 4; ++k){
      const int cid = tid + (k << 8);
      const int row = cid >> 3, u = cid & 7;
      *(uint4*)(As + (row << 6) + (u << 3)) = ra[k];
      *(uint4*)(Bs + (row << 6) + (u << 3)) = rb[k];
    }
    __syncthreads();
#pragma unroll
    for (int ks = 0; ks < 2; ++ks){
      bf16x8 av[4], bvv[4];
#pragma unroll
      for (int i = 0; i < 4; ++i){
        const int rowA = (wy << 6) + (i << 4) + l15;
        av[i] = *(const bf16x8*)(As + (rowA << 6) + (((ks << 2) + quad) << 3));
        const int rowB = (wx << 6) + (i << 4) + l15;
        bvv[i] = *(const bf16x8*)(Bs + (rowB << 6) + (((ks << 2) + quad) << 3));
      }
#pragma unroll
      for (int i = 0; i < 4; ++i)
#pragma unroll
        for (int j = 0; j < 4; ++j)
          acc[i][j] = __builtin_amdgcn_mfma_f32_16x16x32_bf16(av[i], bvv[j], acc[i][j], 0, 0, 0);
    }
  }

  // epilogue: D row (m) = quad*4+reg, col (w) = lane&15.  Channel-major store:
  // one instr = 4 m-rows x 16 lanes x 2B = 4 aligned 32B sectors.
#pragma unroll
  for (int i = 0; i < 4; ++i){
    const int mB = m0 + (wy << 6) + (i << 4) + (quad << 2);
    if (mB < 832){
      const float4 bias = *(const float4*)(ball + mB);
#pragma unroll
      for (int j = 0; j < 4; ++j){
        const int w = w0 + (wx << 6) + (j << 4) + l15;
        const f32x4 rr = acc[i][j];
        const size_t base = (((size_t)(b * 832 + mB)) << 13) + w;
        qkvt[base        ] = f2b(rr.x + bias.x);
        qkvt[base +  8192] = f2b(rr.y + bias.y);
        qkvt[base + 16384] = f2b(rr.z + bias.z);
        qkvt[base + 24576] = f2b(rr.w + bias.w);
      }
    }
  }
}

// ---------------------------------------------------------------------------
// K2: windowed attention (K_ATT=7, reflect pad) + folded conv branch, rewritten
// CHANNEL-MAJOR: one lane per w, one wave per 64-w chunk (wave-private LDS with
// 3+3 halo).  All global accesses are coalesced channel rows (128B reads per
// instr, 256B line stores).  d-loop batched x8 for load ILP.
// grid (32 wtiles of 256, 4 heads, 4 b) x 256 threads.
// ---------------------------------------------------------------------------
__global__ __launch_bounds__(256) void attn_out(const u16* __restrict__ qkvt, const float* __restrict__ wp,
                                                const float* __restrict__ depw, const float* __restrict__ depb,
                                                const float* __restrict__ r1p, const float* __restrict__ r2p,
                                                float* __restrict__ out){
  __shared__ u16 kbuf[4][8][72];   // [wave][row-in-batch][70 used + pad]
  const int wt = blockIdx.x, h = blockIdx.y, b = blockIdx.z;
  const int t = threadIdx.x;
  const int wave = t >> 6, lane = t & 63;
  const int wbase = (wt << 8) + (wave << 6);   // wave's first w
  const int w = wbase + lane;                  // this lane's w

  const size_t qbase = ((size_t)(b * 832 + (h << 6))) << 13;
  const size_t kbase = ((size_t)(b * 832 + 256 + (h << 6))) << 13;
  const size_t vbase = ((size_t)(b * 832 + 512 + (h << 6))) << 13;
  const size_t fbase = ((size_t)(b * 832 + 768 + (h << 4))) << 13;

  float att[7] = {0.f,0.f,0.f,0.f,0.f,0.f,0.f};
  float qd = 0.f;

  // --- phase A: att[kk] = sum_d q[d][w] * k[d][w+kk-3] ; qd = sum_d q*wp ---
  for (int bb = 0; bb < 8; ++bb){
    __syncthreads();   // previous batch's LDS reads done before overwrite
#pragma unroll
    for (int r = 0; r < 8; ++r){
      const int d = (bb << 3) + r;
      const u16* krow = qkvt + kbase + ((size_t)d << 13);
      int ws1 = wbase - 3 + lane;
      ws1 = ws1 < 0 ? -ws1 : ws1;              // left reflect (only at w=0 edge)
      kbuf[wave][r][lane] = krow[ws1];
      if (lane < 6){
        int ws2 = wbase + 61 + lane;           // halo elements 64..69
        ws2 = ws2 > 8191 ? 16382 - ws2 : ws2;  // right reflect
        kbuf[wave][r][64 + lane] = krow[ws2];
      }
    }
    float qv[8];
#pragma unroll
    for (int r = 0; r < 8; ++r)
      qv[r] = b2f(qkvt[qbase + ((size_t)((bb << 3) + r) << 13) + w]);
    __syncthreads();
#pragma unroll
    for (int r = 0; r < 8; ++r){
      const int d = (bb << 3) + r;
      qd += qv[r] * wp[d];
#pragma unroll
      for (int kk = 0; kk < 7; ++kk)
        att[kk] += qv[r] * b2f(kbuf[wave][r][lane + kk]);
    }
  }

  // --- positional term + scale + softmax over the 7-window ---
  const float locw = -1.f + (2.f / 8191.f) * (float)w;
  float mx = -1e30f;
#pragma unroll
  for (int kk = 0; kk < 7; ++kk){
    int wr = w + kk - 3;
    wr = wr < 0 ? -wr : (wr > 8191 ? 16382 - wr : wr);
    const float lr = -1.f + (2.f / 8191.f) * (float)wr;
    att[kk] = 0.125f * (att[kk] + (locw - lr) * qd);
    mx = fmaxf(mx, att[kk]);
  }
  float p[7]; float ssum = 0.f;
#pragma unroll
  for (int kk = 0; kk < 7; ++kk){ p[kk] = __expf(att[kk] - mx); ssum += p[kk]; }
  const float inv = 1.f / ssum;
#pragma unroll
  for (int kk = 0; kk < 7; ++kk) p[kk] *= inv;

  const float r1 = r1p[0];
  const float r2 = r2p[0];

  // --- phase B: out[b][h*64+d][w] = r1*(P.V) + r2*(depw*f + depb) ---
  for (int bb = 0; bb < 8; ++bb){
    __syncthreads();
#pragma unroll
    for (int r = 0; r < 8; ++r){
      const int d = (bb << 3) + r;
      const u16* vrow = qkvt + vbase + ((size_t)d << 13);
      int ws1 = wbase - 3 + lane;
      ws1 = ws1 < 0 ? -ws1 : ws1;
      kbuf[wave][r][lane] = vrow[ws1];
      if (lane < 6){
        int ws2 = wbase + 61 + lane;
        ws2 = ws2 > 8191 ? 16382 - ws2 : ws2;
        kbuf[wave][r][64 + lane] = vrow[ws2];
      }
    }
    float fvv[2];
#pragma unroll
    for (int u = 0; u < 2; ++u)
      fvv[u] = b2f(qkvt[fbase + ((size_t)((bb << 1) + u) << 13) + w]);
    __syncthreads();
#pragma unroll
    for (int r = 0; r < 8; ++r){
      const int d = (bb << 3) + r;
      float o = 0.f;
#pragma unroll
      for (int kk = 0; kk < 7; ++kk)
        o += p[kk] * b2f(kbuf[wave][r][lane + kk]);
      const float oc = depw[(h << 6) + d] * fvv[r >> 2] + depb[(h << 6) + d];
      out[(((size_t)((b << 8) + (h << 6) + d)) << 13) + w] = r1 * o + r2 * oc;
    }
  }
}

// ---------------------------------------------------------------------------
// launch
// ---------------------------------------------------------------------------
extern "C" void kernel_launch(void* const* d_in, const int* in_sizes, int n_in,
                              void* d_out, int out_size, void* d_ws, size_t ws_size,
                              hipStream_t stream){
  (void)in_sizes; (void)n_in; (void)out_size; (void)ws_size;
  const float* x    = (const float*)d_in[0];
  const float* w1   = (const float*)d_in[1];
  const float* b1   = (const float*)d_in[2];
  const float* w2   = (const float*)d_in[3];
  const float* b2   = (const float*)d_in[4];
  const float* w3   = (const float*)d_in[5];
  const float* b3   = (const float*)d_in[6];
  const float* wp   = (const float*)d_in[7];
  // d_in[8] = bp : cancels analytically (pe - unfolded pe), unused
  const float* fcw  = (const float*)d_in[9];
  const float* depw = (const float*)d_in[10];
  const float* depb = (const float*)d_in[11];
  const float* r1p  = (const float*)d_in[12];
  const float* r2p  = (const float*)d_in[13];
  float* out = (float*)d_out;

  char* ws = (char*)d_ws;
  u16*   xt   = (u16*)(ws);                    // 4*8192*256*2   = 16,777,216 B
  u16*   Wall = (u16*)(ws + 16777216);         // 896*256*2      =    458,752 B
  float* ball = (float*)(ws + 17235968);       // 896*4          =      3,584 B
  u16*   qkvt = (u16*)(ws + 17239552);         // 4*832*8192*2   = 54,525,952 B  (channel-major [b][m][w])
                                               // total ~71.8 MB

  k_transpose<<<dim3(128, 4, 4), 256, 0, stream>>>(x, xt);
  k_build<<<dim3(896, 1, 1), 256, 0, stream>>>(w1, b1, w2, b2, w3, b3, fcw, Wall, ball);
  gemm_qkv<<<dim3(7, 256, 1), 256, 0, stream>>>(Wall, ball, xt, qkvt);
  attn_out<<<dim3(32, 4, 4), 256, 0, stream>>>(qkvt, wp, depw, depb, r1p, r2p, out);
}